// Round 9
// baseline (276.229 us; speedup 1.0000x reference)
//
#include <hip/hip_runtime.h>
#include <math.h>

#define N_PTS 50000
#define V_VIEWS 500000
#define IN_MAIN 64
#define IN_MAP 16
#define IN_MOD 128
#define NC 32
#define NC_QK 8
#define SEG_EPS 1e-12f

#define KH_BLOCKS ((V_VIEWS + 63) / 64)   // 7813
#define KA_BLOCKS ((N_PTS + 7) / 8)       // 6250

typedef short bf16x8 __attribute__((ext_vector_type(8)));
typedef float f32x4 __attribute__((ext_vector_type(4)));

static __device__ __forceinline__ short f2bf(float x) {
    union { float f; unsigned u; } v; v.f = x;
    unsigned r = v.u + 0x7fffu + ((v.u >> 16) & 1u);   // RNE
    return (short)(r >> 16);
}

// ws layout (bytes; ws_size ~1 GB):
//   didx    [ 0.0, 2.0 MB)  V int
//   wq      [ 2.0, 8.4 MB)  N*32 f32
//   qb      [ 8.4, 8.6 MB)  N f32
//   ctxw    [ 8.6,15.0 MB)  N*32 f32  — ctxbits (atomicMax) -> ctxW2b in place
//   comp    [15.0,17.0 MB)  V f32
//   segmax  [17.0,17.2 MB)  N f32
//   Wf      [17200000, +32 KB) W_mod1 fragment-linear bf16 (kC B-frags)
//   W1f     [17240000, + 2 KB) W_map1 frag-linear (kH MFMA1 B, k>=16 zero)
//   W2af    [17244000, + 2 KB) W_map2 rows 0..31 frag-linear (kB3 MFMA2 B)
//   W2f     [17248000, +32 KB) W_mod2 fragment-linear bf16 (kD B-frags)
//   invsum  [17300000, +200 KB) N f32
//   hbuf    [17500000, +32 MB)  V*32 bf16 — h=relu(x_map@W1), A-frag layout
// pooled accumulator = d_out's x_pool region, finalized in place by kD.

// ---------------- k0: didx fill + pooled zero + ctxbits zero + W frag builds ----------------
__global__ __launch_bounds__(256) void k0_setup(const int* __restrict__ csr,
                                                const float* __restrict__ Wmod1,
                                                const float* __restrict__ Wmod2,
                                                const float* __restrict__ Wm1,
                                                const float* __restrict__ Wm2,
                                                int* __restrict__ didx,
                                                float* __restrict__ pooled,
                                                float* __restrict__ ctxw,
                                                short* __restrict__ Wf,
                                                short* __restrict__ W1f,
                                                short* __restrict__ W2af,
                                                short* __restrict__ W2f) {
    int t = blockIdx.x * blockDim.x + threadIdx.x;
    int total = gridDim.x * blockDim.x;
    if (t < N_PTS) {
        int a = csr[t], b = csr[t + 1];
        for (int v = a; v < b; ++v) didx[v] = t;
    }
    for (int i = t; i < N_PTS * IN_MOD; i += total) pooled[i] = 0.f;
    for (int i = t; i < N_PTS * NC; i += total) ctxw[i] = 0.f;   // ctxbits init (0.0f)
    for (int i = t; i < IN_MOD * IN_MOD; i += total) {
        int e = i & 7, l = (i >> 3) & 63, j = (i >> 9) & 7, kk = i >> 12;
        int k = kk * 32 + ((l >> 4) << 3) + e;
        int ch = (j << 4) + (l & 15);
        Wf[i] = f2bf(Wmod1[k * IN_MOD + ch]);
        W2f[i] = f2bf(Wmod2[k * IN_MOD + ch]);
    }
    for (int i = t; i < 1024; i += total) {
        int e = i & 7, l = (i >> 3) & 63, j = i >> 9;
        int k = ((l >> 4) << 3) + e;
        int ch = (j << 4) + (l & 15);
        W1f[i] = (k < IN_MAP) ? f2bf(Wm1[k * NC + ch]) : (short)0;
        W2af[i] = f2bf(Wm2[k * NC + ch]);
    }
}

// ---------------- kHA: merged kH (views) + kA (points) in one launch ----------------
// Blocks [0, KH_BLOCKS): kH — dense h=relu(x_map@W1) [MFMA], hbuf store, ctx atomicMax.
// Blocks [KH_BLOCKS, KH_BLOCKS+KA_BLOCKS): kA — x_main -> q -> wq, qb (latency-bound,
// hidden under kH's memory waits by co-residency).
__global__ __launch_bounds__(256) void kHA(
    const float* __restrict__ x_map, const int* __restrict__ didx,
    const short* __restrict__ W1f, int* __restrict__ ctxbits,
    short* __restrict__ hbuf,
    const float* __restrict__ x_main, const float* __restrict__ W1,
    const float* __restrict__ W2, const float* __restrict__ WQ,
    const float* __restrict__ bQ, const float* __restrict__ WK,
    const float* __restrict__ bK,
    float* __restrict__ wq, float* __restrict__ qb) {
    // kH shared
    __shared__ float hl[4][16 * 36];
    // kA shared
    __shared__ float W1l[IN_MAIN * NC];
    __shared__ float W2l[NC * NC];
    __shared__ float WQl[NC * NC_QK];
    __shared__ float WKl[NC * NC_QK];
    __shared__ float bQl[NC_QK];
    __shared__ float bKl[NC_QK];
    __shared__ float h1buf[8][NC];
    __shared__ float h2buf[8][NC];
    __shared__ float qbuf[8][NC_QK];

    int tid = threadIdx.x;
    if (blockIdx.x < KH_BLOCKS) {
        // ================= kH path =================
        int w = tid >> 6, lane = tid & 63;
        int vbase = blockIdx.x * 64 + w * 16;
        if (vbase >= V_VIEWS) return;
        const bf16x8* pW1 = (const bf16x8*)W1f;
        bf16x8 b1a = pW1[lane], b1b = pW1[64 + lane];

        bf16x8 a1 = (bf16x8){0, 0, 0, 0, 0, 0, 0, 0};
        if (lane < 32) {
            const float* xp = x_map + (size_t)(vbase + (lane & 15)) * IN_MAP + ((lane >> 4) << 3);
            float4 x0 = *(const float4*)xp;
            float4 x1 = *(const float4*)(xp + 4);
            a1[0] = f2bf(x0.x); a1[1] = f2bf(x0.y); a1[2] = f2bf(x0.z); a1[3] = f2bf(x0.w);
            a1[4] = f2bf(x1.x); a1[5] = f2bf(x1.y); a1[6] = f2bf(x1.z); a1[7] = f2bf(x1.w);
        }
        f32x4 d1a = (f32x4){0.f, 0.f, 0.f, 0.f}, d1b = (f32x4){0.f, 0.f, 0.f, 0.f};
        d1a = __builtin_amdgcn_mfma_f32_16x16x32_bf16(a1, b1a, d1a, 0, 0, 0);
        d1b = __builtin_amdgcn_mfma_f32_16x16x32_bf16(a1, b1b, d1b, 0, 0, 0);

        int c = lane & 15, kq = lane >> 4;
        int vr0 = kq << 2;
        float* hw = hl[w];
#pragma unroll
        for (int r = 0; r < 4; ++r) {
            hw[(vr0 + r) * 36 + c] = fmaxf(d1a[r], 0.f);
            hw[(vr0 + r) * 36 + c + 16] = fmaxf(d1b[r], 0.f);
        }
        const float* hr = hw + c * 36 + (kq << 3);
        float4 h0 = *(const float4*)hr;
        float4 h1 = *(const float4*)(hr + 4);
        bf16x8 a2;
        a2[0] = f2bf(h0.x); a2[1] = f2bf(h0.y); a2[2] = f2bf(h0.z); a2[3] = f2bf(h0.w);
        a2[4] = f2bf(h1.x); a2[5] = f2bf(h1.y); a2[6] = f2bf(h1.z); a2[7] = f2bf(h1.w);
        *(bf16x8*)(hbuf + (size_t)(vbase + c) * NC + (kq << 3)) = a2;

        int vg = vbase + vr0;
        int4 ss = *(const int4*)(didx + vg);
        const int* sp = (const int*)&ss;
        float ma = 0.f, mb = 0.f;
#pragma unroll
        for (int r = 0; r < 4; ++r) {
            ma = fmaxf(ma, fmaxf(d1a[r], 0.f));
            mb = fmaxf(mb, fmaxf(d1b[r], 0.f));
            bool runend = (r == 3) || (sp[r + 1] != sp[r]);
            if (runend) {
                atomicMax(&ctxbits[sp[r] * NC + c], __float_as_int(ma));
                atomicMax(&ctxbits[sp[r] * NC + c + 16], __float_as_int(mb));
                ma = 0.f; mb = 0.f;
            }
        }
    } else {
        // ================= kA path =================
        int bid = blockIdx.x - KH_BLOCKS;
        for (int i = tid; i < IN_MAIN * NC; i += 256) W1l[i] = W1[i];
        for (int i = tid; i < NC * NC; i += 256) W2l[i] = W2[i];
        for (int i = tid; i < NC * NC_QK; i += 256) WQl[i] = WQ[i];
        for (int i = tid; i < NC * NC_QK; i += 256) WKl[i] = WK[i];
        if (tid < NC_QK) { bQl[tid] = bQ[tid]; bKl[tid] = bK[tid]; }
        __syncthreads();
        int g = tid >> 5, c = tid & 31;
        int p = bid * 8 + g;
        float h1 = 0.f;
        if (p < N_PTS) {
            const float* xr = x_main + (size_t)p * IN_MAIN;
            for (int k = 0; k < IN_MAIN; ++k) h1 += xr[k] * W1l[k * NC + c];
            h1 = fmaxf(h1, 0.f);
        }
        h1buf[g][c] = h1;
        __syncthreads();
        float h2 = 0.f;
        for (int j = 0; j < NC; ++j) h2 += h1buf[g][j] * W2l[j * NC + c];
        h2buf[g][c] = h2;
        __syncthreads();
        if (c < NC_QK) {
            float acc = bQl[c];
            for (int j = 0; j < NC; ++j) acc += h2buf[g][j] * WQl[j * NC_QK + c];
            qbuf[g][c] = acc;
        }
        __syncthreads();
        if (p < N_PTS) {
            float w = 0.f;
            for (int j = 0; j < NC_QK; ++j) w += WKl[c * NC_QK + j] * qbuf[g][j];
            wq[(size_t)p * NC + c] = w;
            if (c == 0) {
                float b = 0.f;
                for (int j = 0; j < NC_QK; ++j) b += bKl[j] * qbuf[g][j];
                qb[p] = b;
            }
        }
    }
}

// ---------------- kB2b: ctxW2b = ctx @ W2b, in place (row-local) ----------------
__global__ __launch_bounds__(256) void kB2b_ctxw(
    const float* __restrict__ Wm2, float* __restrict__ ctxw) {
    __shared__ float W2bl[NC * NC];
    __shared__ float ctxl[8][NC];
    int tid = threadIdx.x;
    for (int i = tid; i < NC * NC; i += 256) W2bl[i] = Wm2[NC * NC + i];
    int g = tid >> 5, c = tid & 31;
    int s = blockIdx.x * 8 + g;
    float cv = (s < N_PTS) ? ctxw[(size_t)s * NC + c] : 0.f;
    ctxl[g][c] = cv;
    __syncthreads();
    if (s < N_PTS) {
        float val = 0.f;
        for (int j = 0; j < NC; ++j) val += ctxl[g][j] * W2bl[j * NC + c];
        ctxw[(size_t)s * NC + c] = val;
    }
}

// ---------------- kB3: dense comp over views [MFMA2 only; h from hbuf] ----------------
__global__ __launch_bounds__(256) void kB3_comp(
    const short* __restrict__ hbuf, const int* __restrict__ didx,
    const short* __restrict__ W2af,
    const float* __restrict__ ctxW2b, const float* __restrict__ wq,
    const float* __restrict__ qb, float* __restrict__ comp) {
    int tid = threadIdx.x;
    int w = tid >> 6, lane = tid & 63;
    int vbase = blockIdx.x * 64 + w * 16;
    if (vbase >= V_VIEWS) return;
    const bf16x8* pW2 = (const bf16x8*)W2af;
    bf16x8 b2a = pW2[lane], b2b = pW2[64 + lane];
    int c = lane & 15, kq = lane >> 4;

    bf16x8 a2 = *(const bf16x8*)(hbuf + (size_t)(vbase + c) * NC + (kq << 3));
    f32x4 d2a = (f32x4){0.f, 0.f, 0.f, 0.f}, d2b = (f32x4){0.f, 0.f, 0.f, 0.f};
    d2a = __builtin_amdgcn_mfma_f32_16x16x32_bf16(a2, b2a, d2a, 0, 0, 0);
    d2b = __builtin_amdgcn_mfma_f32_16x16x32_bf16(a2, b2b, d2b, 0, 0, 0);

    int vr0 = kq << 2;
    int vg = vbase + vr0;
    int4 ss = *(const int4*)(didx + vg);
    const int* sp = (const int*)&ss;
    float part[4];
#pragma unroll
    for (int r = 0; r < 4; ++r) {
        size_t so = (size_t)sp[r] * NC;
        float m0 = fmaxf(d2a[r] + ctxW2b[so + c], 0.f);
        float m1 = fmaxf(d2b[r] + ctxW2b[so + c + 16], 0.f);
        part[r] = m0 * wq[so + c] + m1 * wq[so + c + 16];
    }
#pragma unroll
    for (int mask = 1; mask < 16; mask <<= 1) {
#pragma unroll
        for (int r = 0; r < 4; ++r) part[r] += __shfl_xor(part[r], mask);
    }
    if (c == 0) {
        const float inv_sqrt = 0.35355339059327373f;
        float4 o;
        o.x = (part[0] + qb[sp[0]]) * inv_sqrt;
        o.y = (part[1] + qb[sp[1]]) * inv_sqrt;
        o.z = (part[2] + qb[sp[2]]) * inv_sqrt;
        o.w = (part[3] + qb[sp[3]]) * inv_sqrt;
        *(float4*)(comp + vg) = o;
    }
}

// ---------------- kB4: per-segment softmax stats only (segmax, invsum) ----------------
__global__ __launch_bounds__(256) void kB4_att(
    const float* __restrict__ comp, const int* __restrict__ csr,
    float* __restrict__ segmax, float* __restrict__ invsum) {
    int wid = threadIdx.x >> 6, lane = threadIdx.x & 63;
    int seg = blockIdx.x * 4 + wid;
    if (seg >= N_PTS) return;
    int v0 = csr[seg], v1 = csr[seg + 1];
    if (v0 >= v1) {
        if (lane == 0) { segmax[seg] = 0.f; invsum[seg] = 0.f; }
        return;
    }
    float mx = -__builtin_inff();
    for (int v = v0 + lane; v < v1; v += 64) mx = fmaxf(mx, comp[v]);
    for (int o = 32; o > 0; o >>= 1) mx = fmaxf(mx, __shfl_xor(mx, o));
    float sm = 0.f;
    for (int v = v0 + lane; v < v1; v += 64) sm += __expf(comp[v] - mx);
    for (int o = 32; o > 0; o >>= 1) sm += __shfl_xor(sm, o);
    if (lane == 0) { segmax[seg] = mx; invsum[seg] = 1.f / (sm + SEG_EPS); }
}

// ---------------- kC: pooled += segsum(att * relu(x_mod @ Wmod1))  [bf16 MFMA, 2 tiles] ----------------
// 128 views/block (2 tiles of 64). Tile1's global loads issue right after tile0's
// MFMA so their HBM latency hides under tile0's epilogue + scan. Yl reused.
#define VB2 128
__global__ __launch_bounds__(256) void kC_pool(
    const float* __restrict__ x_mod, const short* __restrict__ Wf,
    const int* __restrict__ didx, const int* __restrict__ csr,
    const float* __restrict__ comp, const float* __restrict__ segmax,
    const float* __restrict__ invsum, float* __restrict__ pooled) {
    __shared__ float Yl[64 * 132];                // 33 KB, reused across tiles
    __shared__ float attl[VB2];
    __shared__ int didxl[VB2];
    int tid = threadIdx.x;
    int vbase = blockIdx.x * VB2;
    if (tid < VB2) {
        int v = vbase + tid;
        if (v < V_VIEWS) {
            int s = didx[v];
            didxl[tid] = s;
            attl[tid] = __expf(comp[v] - segmax[s]) * invsum[s];
        } else {
            didxl[tid] = didx[V_VIEWS - 1];
            attl[tid] = 0.f;
        }
    }
    __syncthreads();

    int w = tid >> 6, lane = tid & 63;
    int row16 = lane & 15;
    int kq = lane >> 4;
    int k0 = kq << 3;

    // ---- tile0 A loads ----
    int v0 = vbase + w * 16 + row16;
    if (v0 >= V_VIEWS) v0 = V_VIEWS - 1;
    const float* xp0 = x_mod + (size_t)v0 * IN_MOD;
    float4 xa[8];
#pragma unroll
    for (int kk = 0; kk < 4; ++kk) {
        xa[kk * 2] = *(const float4*)(xp0 + kk * 32 + k0);
        xa[kk * 2 + 1] = *(const float4*)(xp0 + kk * 32 + k0 + 4);
    }
    // ---- tile0 MFMA ----
    f32x4 acc[8];
    for (int j = 0; j < 8; ++j) acc[j] = (f32x4){0.f, 0.f, 0.f, 0.f};
#pragma unroll
    for (int kk = 0; kk < 4; ++kk) {
        float4 x0 = xa[kk * 2], x1 = xa[kk * 2 + 1];
        bf16x8 a;
        a[0] = f2bf(x0.x); a[1] = f2bf(x0.y); a[2] = f2bf(x0.z); a[3] = f2bf(x0.w);
        a[4] = f2bf(x1.x); a[5] = f2bf(x1.y); a[6] = f2bf(x1.z); a[7] = f2bf(x1.w);
        const bf16x8* wf = (const bf16x8*)(Wf + ((size_t)(kk * 8) * 64 + lane) * 8);
#pragma unroll
        for (int j = 0; j < 8; ++j) {
            bf16x8 b = wf[j * 64];
            acc[j] = __builtin_amdgcn_mfma_f32_16x16x32_bf16(a, b, acc[j], 0, 0, 0);
        }
    }
    // ---- tile1 A loads issued here (latency hides under epilogue+scan of tile0) ----
    int v1 = vbase + 64 + w * 16 + row16;
    if (v1 >= V_VIEWS) v1 = V_VIEWS - 1;          // att=0 handles padding
    const float* xp1 = x_mod + (size_t)v1 * IN_MOD;
    float4 xb[8];
#pragma unroll
    for (int kk = 0; kk < 4; ++kk) {
        xb[kk * 2] = *(const float4*)(xp1 + kk * 32 + k0);
        xb[kk * 2 + 1] = *(const float4*)(xp1 + kk * 32 + k0 + 4);
    }
    // ---- tile0 epilogue ----
#pragma unroll
    for (int j = 0; j < 8; ++j) {
        int ch = j * 16 + row16;
        int rbase = w * 16 + (kq << 2);
#pragma unroll
        for (int r = 0; r < 4; ++r) {
            int rw = rbase + r;
            Yl[rw * 132 + ch] = fmaxf(acc[j][r], 0.f) * attl[rw];
        }
    }
    __syncthreads();
    // ---- tile0 scan (rows 0..63 = att idx 0..63) ----
    {
        int halfid = tid >> 7, cc = tid & 127;
        int r0 = halfid << 5;
        int hb = vbase + r0;
        float s_acc = 0.f;
        int cur = didxl[r0];
        for (int r = r0; r < r0 + 32; ++r) {
            int s = didxl[r];
            if (s != cur) {
                if (csr[cur] >= hb && csr[cur + 1] <= hb + 32)
                    pooled[(size_t)cur * IN_MOD + cc] = s_acc;
                else
                    atomicAdd(&pooled[(size_t)cur * IN_MOD + cc], s_acc);
                s_acc = 0.f; cur = s;
            }
            s_acc += Yl[r * 132 + cc];
        }
        if (csr[cur] >= hb && csr[cur + 1] <= hb + 32)
            pooled[(size_t)cur * IN_MOD + cc] = s_acc;
        else
            atomicAdd(&pooled[(size_t)cur * IN_MOD + cc], s_acc);
    }
    __syncthreads();
    // ---- tile1 MFMA ----
    for (int j = 0; j < 8; ++j) acc[j] = (f32x4){0.f, 0.f, 0.f, 0.f};
#pragma unroll
    for (int kk = 0; kk < 4; ++kk) {
        float4 x0 = xb[kk * 2], x1 = xb[kk * 2 + 1];
        bf16x8 a;
        a[0] = f2bf(x0.x); a[1] = f2bf(x0.y); a[2] = f2bf(x0.z); a[3] = f2bf(x0.w);
        a[4] = f2bf(x1.x); a[5] = f2bf(x1.y); a[6] = f2bf(x1.z); a[7] = f2bf(x1.w);
        const bf16x8* wf = (const bf16x8*)(Wf + ((size_t)(kk * 8) * 64 + lane) * 8);
#pragma unroll
        for (int j = 0; j < 8; ++j) {
            bf16x8 b = wf[j * 64];
            acc[j] = __builtin_amdgcn_mfma_f32_16x16x32_bf16(a, b, acc[j], 0, 0, 0);
        }
    }
    // ---- tile1 epilogue ----
#pragma unroll
    for (int j = 0; j < 8; ++j) {
        int ch = j * 16 + row16;
        int rbase = w * 16 + (kq << 2);
#pragma unroll
        for (int r = 0; r < 4; ++r) {
            int rw = rbase + r;
            Yl[rw * 132 + ch] = fmaxf(acc[j][r], 0.f) * attl[64 + rw];
        }
    }
    __syncthreads();
    // ---- tile1 scan (Yl rows 0..63 = att idx 64..127) ----
    {
        int halfid = tid >> 7, cc = tid & 127;
        int r0 = halfid << 5;
        int hb = vbase + 64 + r0;
        float s_acc = 0.f;
        int cur = didxl[64 + r0];
        for (int r = r0; r < r0 + 32; ++r) {
            int s = didxl[64 + r];
            if (s != cur) {
                if (csr[cur] >= hb && csr[cur + 1] <= hb + 32)
                    pooled[(size_t)cur * IN_MOD + cc] = s_acc;
                else
                    atomicAdd(&pooled[(size_t)cur * IN_MOD + cc], s_acc);
                s_acc = 0.f; cur = s;
            }
            s_acc += Yl[r * 132 + cc];
        }
        if (csr[cur] >= hb && csr[cur + 1] <= hb + 32)
            pooled[(size_t)cur * IN_MOD + cc] = s_acc;
        else
            atomicAdd(&pooled[(size_t)cur * IN_MOD + cc], s_acc);
    }
}

// ---------------- kD: out = (pooled @ Wmod2) * gate, in place [bf16 MFMA]; x_seen ----------------
__global__ __launch_bounds__(256) void kD_final(
    const short* __restrict__ W2f,
    const float* __restrict__ segmax, const int* __restrict__ csr,
    const float* __restrict__ g_w, const float* __restrict__ g_b,
    float* __restrict__ out) {
    int tid = threadIdx.x;
    int w = tid >> 6, lane = tid & 63;
    int row16 = lane & 15;
    int kq = lane >> 4;
    int k0 = kq << 3;
    int rbase = blockIdx.x * 64 + w * 16;
    float gw = g_w[0], gb = g_b[0];

    int rr = rbase + row16;
    if (rr >= N_PTS) rr = N_PTS - 1;              // clamped read; writes masked below
    const float* xp = out + (size_t)rr * IN_MOD;

    f32x4 acc[8];
    for (int j = 0; j < 8; ++j) acc[j] = (f32x4){0.f, 0.f, 0.f, 0.f};
#pragma unroll
    for (int kk = 0; kk < 4; ++kk) {
        float4 x0 = *(const float4*)(xp + kk * 32 + k0);
        float4 x1 = *(const float4*)(xp + kk * 32 + k0 + 4);
        bf16x8 a;
        a[0] = f2bf(x0.x); a[1] = f2bf(x0.y); a[2] = f2bf(x0.z); a[3] = f2bf(x0.w);
        a[4] = f2bf(x1.x); a[5] = f2bf(x1.y); a[6] = f2bf(x1.z); a[7] = f2bf(x1.w);
        const bf16x8* wf = (const bf16x8*)(W2f + ((size_t)(kk * 8) * 64 + lane) * 8);
#pragma unroll
        for (int j = 0; j < 8; ++j) {
            bf16x8 b = wf[j * 64];
            acc[j] = __builtin_amdgcn_mfma_f32_16x16x32_bf16(a, b, acc[j], 0, 0, 0);
        }
    }
    float gate[4];
    int rowv[4];
#pragma unroll
    for (int r = 0; r < 4; ++r) {
        int ro = rbase + (kq << 2) + r;
        rowv[r] = ro;
        if (ro < N_PTS) {
            bool nz = csr[ro + 1] > csr[ro];
            float gin = nz ? segmax[ro] : 0.f;
            gate[r] = tanhf(fmaxf(gw * gin + gb, 0.f));
            if (row16 == 0) out[(size_t)N_PTS * IN_MOD + ro] = nz ? 1.f : 0.f;
        } else {
            gate[r] = 0.f;
        }
    }
#pragma unroll
    for (int j = 0; j < 8; ++j) {
        int ch = j * 16 + row16;
#pragma unroll
        for (int r = 0; r < 4; ++r) {
            if (rowv[r] < N_PTS)
                out[(size_t)rowv[r] * IN_MOD + ch] = acc[j][r] * gate[r];
        }
    }
}

extern "C" void kernel_launch(void* const* d_in, const int* in_sizes, int n_in,
                              void* d_out, int out_size, void* d_ws, size_t ws_size,
                              hipStream_t stream) {
    (void)in_sizes; (void)n_in; (void)out_size; (void)ws_size;
    const float* x_main = (const float*)d_in[0];
    const float* x_mod  = (const float*)d_in[1];
    const float* x_map  = (const float*)d_in[2];
    const int*   csr    = (const int*)d_in[3];
    const float* W_main1 = (const float*)d_in[4];
    const float* W_main2 = (const float*)d_in[5];
    const float* W_map1  = (const float*)d_in[6];
    const float* W_map2  = (const float*)d_in[7];
    const float* W_mod1  = (const float*)d_in[8];
    const float* W_mod2  = (const float*)d_in[9];
    const float* WQ = (const float*)d_in[10];
    const float* bQ = (const float*)d_in[11];
    const float* WK = (const float*)d_in[12];
    const float* bK = (const float*)d_in[13];
    const float* g_w = (const float*)d_in[14];
    const float* g_b = (const float*)d_in[15];
    float* out = (float*)d_out;

    char* ws = (char*)d_ws;
    int*   didx   = (int*)ws;                       // [ 0.0,  2.0 MB)
    float* wq     = (float*)(ws + 2000000);         // [ 2.0,  8.4 MB)
    float* qb     = (float*)(ws + 8400000);         // [ 8.4,  8.6 MB)
    float* ctxw   = (float*)(ws + 8600000);         // [ 8.6, 15.0 MB)  ctxbits -> ctxW2b
    float* comp   = (float*)(ws + 15000000);        // [15.0, 17.0 MB)
    float* segmax = (float*)(ws + 17000000);        // [17.0, 17.2 MB)
    short* Wf     = (short*)(ws + 17200000);        // 32 KB
    short* W1f    = (short*)(ws + 17240000);        // 2 KB
    short* W2af   = (short*)(ws + 17244000);        // 2 KB
    short* W2f    = (short*)(ws + 17248000);        // 32 KB
    float* invsum = (float*)(ws + 17300000);        // 200 KB
    short* hbuf   = (short*)(ws + 17500000);        // 32 MB
    float* pooled = out;

    k0_setup<<<512, 256, 0, stream>>>(csr, W_mod1, W_mod2, W_map1, W_map2,
                                      didx, pooled, ctxw, Wf, W1f, W2af, W2f);
    kHA<<<KH_BLOCKS + KA_BLOCKS, 256, 0, stream>>>(x_map, didx, W1f, (int*)ctxw, hbuf,
                                                   x_main, W_main1, W_main2, WQ, bQ,
                                                   WK, bK, wq, qb);
    kB2b_ctxw<<<(N_PTS + 7) / 8, 256, 0, stream>>>(W_map2, ctxw);
    kB3_comp<<<(V_VIEWS + 63) / 64, 256, 0, stream>>>(hbuf, didx, W2af,
                                                      ctxw, wq, qb, comp);
    kB4_att<<<(N_PTS + 3) / 4, 256, 0, stream>>>(comp, csr, segmax, invsum);
    kC_pool<<<(V_VIEWS + VB2 - 1) / VB2, 256, 0, stream>>>(x_mod, Wf, didx, csr,
                                                           comp, segmax, invsum, pooled);
    kD_final<<<(N_PTS + 63) / 64, 256, 0, stream>>>(W2f, segmax, csr, g_w, g_b, out);
}

// Round 10
// 221.551 us; speedup vs baseline: 1.2468x; 1.2468x over previous
//
#include <hip/hip_runtime.h>
#include <math.h>

#define N_PTS 50000
#define V_VIEWS 500000
#define IN_MAIN 64
#define IN_MAP 16
#define IN_MOD 128
#define NC 32
#define NC_QK 8
#define SEG_EPS 1e-12f

#define KH_BLOCKS ((V_VIEWS + 63) / 64)   // 7813
#define KA_BLOCKS ((N_PTS + 7) / 8)       // 6250

typedef short bf16x8 __attribute__((ext_vector_type(8)));
typedef float f32x4 __attribute__((ext_vector_type(4)));

static __device__ __forceinline__ short f2bf(float x) {
    union { float f; unsigned u; } v; v.f = x;
    unsigned r = v.u + 0x7fffu + ((v.u >> 16) & 1u);   // RNE
    return (short)(r >> 16);
}
static __device__ __forceinline__ float bf2f(unsigned short b) {
    union { unsigned u; float f; } v; v.u = ((unsigned)b) << 16; return v.f;
}

// ws layout (bytes; ws_size ~1 GB):
//   didx    [ 0.0, 2.0 MB)  V int
//   wq      [ 2.0, 8.4 MB)  N*32 f32
//   qb      [ 8.4, 8.6 MB)  N f32
//   ctxw    [ 8.6,15.0 MB)  N*32 f32  — ctxbits (atomicMax) -> ctxW2b in place
//   comp    [15.0,17.0 MB)  V f32
//   segmax  [17.0,17.2 MB)  N f32
//   Wf      [17200000, +32 KB) W_mod1 fragment-linear bf16 (kC B-frags)
//   W1f     [17240000, + 2 KB) W_map1 frag-linear (kH MFMA1 B, k>=16 zero)
//   W2af    [17244000, + 2 KB) W_map2 rows 0..31 frag-linear (kB3 MFMA2 B)
//   W2f     [17248000, +32 KB) W_mod2 fragment-linear bf16 (kD B-frags)
//   invsum  [17300000, +200 KB) N f32
//   hbuf    [17500000, +32 MB)  V*32 bf16 — h=relu(x_map@W1), A-frag layout
// pooled accumulator = d_out's x_pool region, finalized in place by kD.

// ---------------- k0: didx fill + pooled zero + ctxbits zero + W frag builds ----------------
__global__ __launch_bounds__(256) void k0_setup(const int* __restrict__ csr,
                                                const float* __restrict__ Wmod1,
                                                const float* __restrict__ Wmod2,
                                                const float* __restrict__ Wm1,
                                                const float* __restrict__ Wm2,
                                                int* __restrict__ didx,
                                                float* __restrict__ pooled,
                                                float* __restrict__ ctxw,
                                                short* __restrict__ Wf,
                                                short* __restrict__ W1f,
                                                short* __restrict__ W2af,
                                                short* __restrict__ W2f) {
    int t = blockIdx.x * blockDim.x + threadIdx.x;
    int total = gridDim.x * blockDim.x;
    if (t < N_PTS) {
        int a = csr[t], b = csr[t + 1];
        for (int v = a; v < b; ++v) didx[v] = t;
    }
    for (int i = t; i < N_PTS * IN_MOD; i += total) pooled[i] = 0.f;
    for (int i = t; i < N_PTS * NC; i += total) ctxw[i] = 0.f;   // ctxbits init (0.0f)
    for (int i = t; i < IN_MOD * IN_MOD; i += total) {
        int e = i & 7, l = (i >> 3) & 63, j = (i >> 9) & 7, kk = i >> 12;
        int k = kk * 32 + ((l >> 4) << 3) + e;
        int ch = (j << 4) + (l & 15);
        Wf[i] = f2bf(Wmod1[k * IN_MOD + ch]);
        W2f[i] = f2bf(Wmod2[k * IN_MOD + ch]);
    }
    for (int i = t; i < 1024; i += total) {
        int e = i & 7, l = (i >> 3) & 63, j = i >> 9;
        int k = ((l >> 4) << 3) + e;
        int ch = (j << 4) + (l & 15);
        W1f[i] = (k < IN_MAP) ? f2bf(Wm1[k * NC + ch]) : (short)0;
        W2af[i] = f2bf(Wm2[k * NC + ch]);
    }
}

// ---------------- kHA: merged kH (views) + kA (points) in one launch ----------------
__global__ __launch_bounds__(256) void kHA(
    const float* __restrict__ x_map, const int* __restrict__ didx,
    const short* __restrict__ W1f, int* __restrict__ ctxbits,
    short* __restrict__ hbuf,
    const float* __restrict__ x_main, const float* __restrict__ W1,
    const float* __restrict__ W2, const float* __restrict__ WQ,
    const float* __restrict__ bQ, const float* __restrict__ WK,
    const float* __restrict__ bK,
    float* __restrict__ wq, float* __restrict__ qb) {
    __shared__ float hl[4][16 * 36];
    __shared__ float W1l[IN_MAIN * NC];
    __shared__ float W2l[NC * NC];
    __shared__ float WQl[NC * NC_QK];
    __shared__ float WKl[NC * NC_QK];
    __shared__ float bQl[NC_QK];
    __shared__ float bKl[NC_QK];
    __shared__ float h1buf[8][NC];
    __shared__ float h2buf[8][NC];
    __shared__ float qbuf[8][NC_QK];

    int tid = threadIdx.x;
    if (blockIdx.x < KH_BLOCKS) {
        // ================= kH path =================
        int w = tid >> 6, lane = tid & 63;
        int vbase = blockIdx.x * 64 + w * 16;
        if (vbase >= V_VIEWS) return;
        const bf16x8* pW1 = (const bf16x8*)W1f;
        bf16x8 b1a = pW1[lane], b1b = pW1[64 + lane];

        bf16x8 a1 = (bf16x8){0, 0, 0, 0, 0, 0, 0, 0};
        if (lane < 32) {
            const float* xp = x_map + (size_t)(vbase + (lane & 15)) * IN_MAP + ((lane >> 4) << 3);
            float4 x0 = *(const float4*)xp;
            float4 x1 = *(const float4*)(xp + 4);
            a1[0] = f2bf(x0.x); a1[1] = f2bf(x0.y); a1[2] = f2bf(x0.z); a1[3] = f2bf(x0.w);
            a1[4] = f2bf(x1.x); a1[5] = f2bf(x1.y); a1[6] = f2bf(x1.z); a1[7] = f2bf(x1.w);
        }
        f32x4 d1a = (f32x4){0.f, 0.f, 0.f, 0.f}, d1b = (f32x4){0.f, 0.f, 0.f, 0.f};
        d1a = __builtin_amdgcn_mfma_f32_16x16x32_bf16(a1, b1a, d1a, 0, 0, 0);
        d1b = __builtin_amdgcn_mfma_f32_16x16x32_bf16(a1, b1b, d1b, 0, 0, 0);

        int c = lane & 15, kq = lane >> 4;
        int vr0 = kq << 2;
        float* hw = hl[w];
#pragma unroll
        for (int r = 0; r < 4; ++r) {
            hw[(vr0 + r) * 36 + c] = fmaxf(d1a[r], 0.f);
            hw[(vr0 + r) * 36 + c + 16] = fmaxf(d1b[r], 0.f);
        }
        const float* hr = hw + c * 36 + (kq << 3);
        float4 h0 = *(const float4*)hr;
        float4 h1 = *(const float4*)(hr + 4);
        bf16x8 a2;
        a2[0] = f2bf(h0.x); a2[1] = f2bf(h0.y); a2[2] = f2bf(h0.z); a2[3] = f2bf(h0.w);
        a2[4] = f2bf(h1.x); a2[5] = f2bf(h1.y); a2[6] = f2bf(h1.z); a2[7] = f2bf(h1.w);
        *(bf16x8*)(hbuf + (size_t)(vbase + c) * NC + (kq << 3)) = a2;

        int vg = vbase + vr0;
        int4 ss = *(const int4*)(didx + vg);
        const int* sp = (const int*)&ss;
        float ma = 0.f, mb = 0.f;
#pragma unroll
        for (int r = 0; r < 4; ++r) {
            ma = fmaxf(ma, fmaxf(d1a[r], 0.f));
            mb = fmaxf(mb, fmaxf(d1b[r], 0.f));
            bool runend = (r == 3) || (sp[r + 1] != sp[r]);
            if (runend) {
                atomicMax(&ctxbits[sp[r] * NC + c], __float_as_int(ma));
                atomicMax(&ctxbits[sp[r] * NC + c + 16], __float_as_int(mb));
                ma = 0.f; mb = 0.f;
            }
        }
    } else {
        // ================= kA path =================
        int bid = blockIdx.x - KH_BLOCKS;
        for (int i = tid; i < IN_MAIN * NC; i += 256) W1l[i] = W1[i];
        for (int i = tid; i < NC * NC; i += 256) W2l[i] = W2[i];
        for (int i = tid; i < NC * NC_QK; i += 256) WQl[i] = WQ[i];
        for (int i = tid; i < NC * NC_QK; i += 256) WKl[i] = WK[i];
        if (tid < NC_QK) { bQl[tid] = bQ[tid]; bKl[tid] = bK[tid]; }
        __syncthreads();
        int g = tid >> 5, c = tid & 31;
        int p = bid * 8 + g;
        float h1 = 0.f;
        if (p < N_PTS) {
            const float* xr = x_main + (size_t)p * IN_MAIN;
            for (int k = 0; k < IN_MAIN; ++k) h1 += xr[k] * W1l[k * NC + c];
            h1 = fmaxf(h1, 0.f);
        }
        h1buf[g][c] = h1;
        __syncthreads();
        float h2 = 0.f;
        for (int j = 0; j < NC; ++j) h2 += h1buf[g][j] * W2l[j * NC + c];
        h2buf[g][c] = h2;
        __syncthreads();
        if (c < NC_QK) {
            float acc = bQl[c];
            for (int j = 0; j < NC; ++j) acc += h2buf[g][j] * WQl[j * NC_QK + c];
            qbuf[g][c] = acc;
        }
        __syncthreads();
        if (p < N_PTS) {
            float w = 0.f;
            for (int j = 0; j < NC_QK; ++j) w += WKl[c * NC_QK + j] * qbuf[g][j];
            wq[(size_t)p * NC + c] = w;
            if (c == 0) {
                float b = 0.f;
                for (int j = 0; j < NC_QK; ++j) b += bKl[j] * qbuf[g][j];
                qb[p] = b;
            }
        }
    }
}

// ---------------- kB2b: ctxW2b = ctx @ W2b, in place (row-local) ----------------
__global__ __launch_bounds__(256) void kB2b_ctxw(
    const float* __restrict__ Wm2, float* __restrict__ ctxw) {
    __shared__ float W2bl[NC * NC];
    __shared__ float ctxl[8][NC];
    int tid = threadIdx.x;
    for (int i = tid; i < NC * NC; i += 256) W2bl[i] = Wm2[NC * NC + i];
    int g = tid >> 5, c = tid & 31;
    int s = blockIdx.x * 8 + g;
    float cv = (s < N_PTS) ? ctxw[(size_t)s * NC + c] : 0.f;
    ctxl[g][c] = cv;
    __syncthreads();
    if (s < N_PTS) {
        float val = 0.f;
        for (int j = 0; j < NC; ++j) val += ctxl[g][j] * W2bl[j * NC + c];
        ctxw[(size_t)s * NC + c] = val;
    }
}

// ---------------- kB3: dense comp over views [MFMA2 only; h from hbuf] ----------------
__global__ __launch_bounds__(256) void kB3_comp(
    const short* __restrict__ hbuf, const int* __restrict__ didx,
    const short* __restrict__ W2af,
    const float* __restrict__ ctxW2b, const float* __restrict__ wq,
    const float* __restrict__ qb, float* __restrict__ comp) {
    int tid = threadIdx.x;
    int w = tid >> 6, lane = tid & 63;
    int vbase = blockIdx.x * 64 + w * 16;
    if (vbase >= V_VIEWS) return;
    const bf16x8* pW2 = (const bf16x8*)W2af;
    bf16x8 b2a = pW2[lane], b2b = pW2[64 + lane];
    int c = lane & 15, kq = lane >> 4;

    bf16x8 a2 = *(const bf16x8*)(hbuf + (size_t)(vbase + c) * NC + (kq << 3));
    f32x4 d2a = (f32x4){0.f, 0.f, 0.f, 0.f}, d2b = (f32x4){0.f, 0.f, 0.f, 0.f};
    d2a = __builtin_amdgcn_mfma_f32_16x16x32_bf16(a2, b2a, d2a, 0, 0, 0);
    d2b = __builtin_amdgcn_mfma_f32_16x16x32_bf16(a2, b2b, d2b, 0, 0, 0);

    int vr0 = kq << 2;
    int vg = vbase + vr0;
    int4 ss = *(const int4*)(didx + vg);
    const int* sp = (const int*)&ss;
    float part[4];
#pragma unroll
    for (int r = 0; r < 4; ++r) {
        size_t so = (size_t)sp[r] * NC;
        float m0 = fmaxf(d2a[r] + ctxW2b[so + c], 0.f);
        float m1 = fmaxf(d2b[r] + ctxW2b[so + c + 16], 0.f);
        part[r] = m0 * wq[so + c] + m1 * wq[so + c + 16];
    }
#pragma unroll
    for (int mask = 1; mask < 16; mask <<= 1) {
#pragma unroll
        for (int r = 0; r < 4; ++r) part[r] += __shfl_xor(part[r], mask);
    }
    if (c == 0) {
        const float inv_sqrt = 0.35355339059327373f;
        float4 o;
        o.x = (part[0] + qb[sp[0]]) * inv_sqrt;
        o.y = (part[1] + qb[sp[1]]) * inv_sqrt;
        o.z = (part[2] + qb[sp[2]]) * inv_sqrt;
        o.w = (part[3] + qb[sp[3]]) * inv_sqrt;
        *(float4*)(comp + vg) = o;
    }
}

// ---------------- kB4: per-segment softmax stats only (segmax, invsum) ----------------
__global__ __launch_bounds__(256) void kB4_att(
    const float* __restrict__ comp, const int* __restrict__ csr,
    float* __restrict__ segmax, float* __restrict__ invsum) {
    int wid = threadIdx.x >> 6, lane = threadIdx.x & 63;
    int seg = blockIdx.x * 4 + wid;
    if (seg >= N_PTS) return;
    int v0 = csr[seg], v1 = csr[seg + 1];
    if (v0 >= v1) {
        if (lane == 0) { segmax[seg] = 0.f; invsum[seg] = 0.f; }
        return;
    }
    float mx = -__builtin_inff();
    for (int v = v0 + lane; v < v1; v += 64) mx = fmaxf(mx, comp[v]);
    for (int o = 32; o > 0; o >>= 1) mx = fmaxf(mx, __shfl_xor(mx, o));
    float sm = 0.f;
    for (int v = v0 + lane; v < v1; v += 64) sm += __expf(comp[v] - mx);
    for (int o = 32; o > 0; o >>= 1) sm += __shfl_xor(sm, o);
    if (lane == 0) { segmax[seg] = mx; invsum[seg] = 1.f / (sm + SEG_EPS); }
}

// ---------------- kC: pooled += segsum(att * relu(x_mod @ Wmod1))  [bf16 MFMA] ----------------
// Single 64-view tile (R8 structure). Latency fixes: bf16 Y staging (17 KB LDS ->
// 8 blocks/CU), per-row csr bounds staged in LDS, chunked register-batched scan.
#define VB 64
__global__ __launch_bounds__(256) void kC_pool(
    const float* __restrict__ x_mod, const short* __restrict__ Wf,
    const int* __restrict__ didx, const int* __restrict__ csr,
    const float* __restrict__ comp, const float* __restrict__ segmax,
    const float* __restrict__ invsum, float* __restrict__ pooled) {
    __shared__ unsigned short Ybl[VB * 136];      // 17.4 KB, bf16, stride 136
    __shared__ float attl[VB];
    __shared__ int didxl[VB];
    __shared__ int csrAl[VB];                     // csr[s] per row
    __shared__ int csrBl[VB];                     // csr[s+1] per row
    int tid = threadIdx.x;
    int vbase = blockIdx.x * VB;
    if (tid < VB) {
        int v = vbase + tid;
        if (v < V_VIEWS) {
            int s = didx[v];
            didxl[tid] = s;
            attl[tid] = __expf(comp[v] - segmax[s]) * invsum[s];
            csrAl[tid] = csr[s];
            csrBl[tid] = csr[s + 1];
        } else {
            int s = didx[V_VIEWS - 1];
            didxl[tid] = s;
            attl[tid] = 0.f;
            csrAl[tid] = csr[s];
            csrBl[tid] = csr[s + 1];
        }
    }
    __syncthreads();

    int w = tid >> 6, lane = tid & 63;
    int row16 = lane & 15;
    int kq = lane >> 4;
    int k0 = kq << 3;
    f32x4 acc[8];
    for (int j = 0; j < 8; ++j) acc[j] = (f32x4){0.f, 0.f, 0.f, 0.f};

    int v = vbase + w * 16 + row16;
    if (v >= V_VIEWS) v = V_VIEWS - 1;            // att=0 handles padding
    const float* xp = x_mod + (size_t)v * IN_MOD;

#pragma unroll
    for (int kk = 0; kk < 4; ++kk) {
        float4 x0 = *(const float4*)(xp + kk * 32 + k0);
        float4 x1 = *(const float4*)(xp + kk * 32 + k0 + 4);
        bf16x8 a;
        a[0] = f2bf(x0.x); a[1] = f2bf(x0.y); a[2] = f2bf(x0.z); a[3] = f2bf(x0.w);
        a[4] = f2bf(x1.x); a[5] = f2bf(x1.y); a[6] = f2bf(x1.z); a[7] = f2bf(x1.w);
        const bf16x8* wf = (const bf16x8*)(Wf + ((size_t)(kk * 8) * 64 + lane) * 8);
#pragma unroll
        for (int j = 0; j < 8; ++j) {
            bf16x8 b = wf[j * 64];
            acc[j] = __builtin_amdgcn_mfma_f32_16x16x32_bf16(a, b, acc[j], 0, 0, 0);
        }
    }
    // epilogue: relu, att-scale, stage bf16 (C/D: col=lane&15, row=(lane>>4)*4+r)
#pragma unroll
    for (int j = 0; j < 8; ++j) {
        int ch = j * 16 + row16;
        int rbase = w * 16 + (kq << 2);
#pragma unroll
        for (int r = 0; r < 4; ++r) {
            int rw = rbase + r;
            Ybl[rw * 136 + ch] = (unsigned short)f2bf(fmaxf(acc[j][r], 0.f) * attl[rw]);
        }
    }
    __syncthreads();
    // segmented scan: half h covers rows [h*32, h*32+32), all 256 threads active.
    // Chunked register batch: 8 LDS loads issue independently, then serial accumulate.
    {
        int halfid = tid >> 7, cc = tid & 127;
        int r0 = halfid << 5;
        int hb = vbase + r0;
        float s_acc = 0.f;
        int cur = didxl[r0];
        int curA = csrAl[r0], curB = csrBl[r0];
        for (int rc = 0; rc < 32; rc += 8) {
            float yv[8];
#pragma unroll
            for (int u = 0; u < 8; ++u) yv[u] = bf2f(Ybl[(r0 + rc + u) * 136 + cc]);
#pragma unroll
            for (int u = 0; u < 8; ++u) {
                int r = r0 + rc + u;
                int s = didxl[r];
                if (s != cur) {
                    if (curA >= hb && curB <= hb + 32)
                        pooled[(size_t)cur * IN_MOD + cc] = s_acc;
                    else
                        atomicAdd(&pooled[(size_t)cur * IN_MOD + cc], s_acc);
                    s_acc = 0.f; cur = s; curA = csrAl[r]; curB = csrBl[r];
                }
                s_acc += yv[u];
            }
        }
        if (curA >= hb && curB <= hb + 32)
            pooled[(size_t)cur * IN_MOD + cc] = s_acc;
        else
            atomicAdd(&pooled[(size_t)cur * IN_MOD + cc], s_acc);
    }
}

// ---------------- kD: out = (pooled @ Wmod2) * gate, in place [bf16 MFMA]; x_seen ----------------
__global__ __launch_bounds__(256) void kD_final(
    const short* __restrict__ W2f,
    const float* __restrict__ segmax, const int* __restrict__ csr,
    const float* __restrict__ g_w, const float* __restrict__ g_b,
    float* __restrict__ out) {
    int tid = threadIdx.x;
    int w = tid >> 6, lane = tid & 63;
    int row16 = lane & 15;
    int kq = lane >> 4;
    int k0 = kq << 3;
    int rbase = blockIdx.x * 64 + w * 16;
    float gw = g_w[0], gb = g_b[0];

    int rr = rbase + row16;
    if (rr >= N_PTS) rr = N_PTS - 1;              // clamped read; writes masked below
    const float* xp = out + (size_t)rr * IN_MOD;

    f32x4 acc[8];
    for (int j = 0; j < 8; ++j) acc[j] = (f32x4){0.f, 0.f, 0.f, 0.f};
#pragma unroll
    for (int kk = 0; kk < 4; ++kk) {
        float4 x0 = *(const float4*)(xp + kk * 32 + k0);
        float4 x1 = *(const float4*)(xp + kk * 32 + k0 + 4);
        bf16x8 a;
        a[0] = f2bf(x0.x); a[1] = f2bf(x0.y); a[2] = f2bf(x0.z); a[3] = f2bf(x0.w);
        a[4] = f2bf(x1.x); a[5] = f2bf(x1.y); a[6] = f2bf(x1.z); a[7] = f2bf(x1.w);
        const bf16x8* wf = (const bf16x8*)(W2f + ((size_t)(kk * 8) * 64 + lane) * 8);
#pragma unroll
        for (int j = 0; j < 8; ++j) {
            bf16x8 b = wf[j * 64];
            acc[j] = __builtin_amdgcn_mfma_f32_16x16x32_bf16(a, b, acc[j], 0, 0, 0);
        }
    }
    float gate[4];
    int rowv[4];
#pragma unroll
    for (int r = 0; r < 4; ++r) {
        int ro = rbase + (kq << 2) + r;
        rowv[r] = ro;
        if (ro < N_PTS) {
            bool nz = csr[ro + 1] > csr[ro];
            float gin = nz ? segmax[ro] : 0.f;
            gate[r] = tanhf(fmaxf(gw * gin + gb, 0.f));
            if (row16 == 0) out[(size_t)N_PTS * IN_MOD + ro] = nz ? 1.f : 0.f;
        } else {
            gate[r] = 0.f;
        }
    }
#pragma unroll
    for (int j = 0; j < 8; ++j) {
        int ch = j * 16 + row16;
#pragma unroll
        for (int r = 0; r < 4; ++r) {
            if (rowv[r] < N_PTS)
                out[(size_t)rowv[r] * IN_MOD + ch] = acc[j][r] * gate[r];
        }
    }
}

extern "C" void kernel_launch(void* const* d_in, const int* in_sizes, int n_in,
                              void* d_out, int out_size, void* d_ws, size_t ws_size,
                              hipStream_t stream) {
    (void)in_sizes; (void)n_in; (void)out_size; (void)ws_size;
    const float* x_main = (const float*)d_in[0];
    const float* x_mod  = (const float*)d_in[1];
    const float* x_map  = (const float*)d_in[2];
    const int*   csr    = (const int*)d_in[3];
    const float* W_main1 = (const float*)d_in[4];
    const float* W_main2 = (const float*)d_in[5];
    const float* W_map1  = (const float*)d_in[6];
    const float* W_map2  = (const float*)d_in[7];
    const float* W_mod1  = (const float*)d_in[8];
    const float* W_mod2  = (const float*)d_in[9];
    const float* WQ = (const float*)d_in[10];
    const float* bQ = (const float*)d_in[11];
    const float* WK = (const float*)d_in[12];
    const float* bK = (const float*)d_in[13];
    const float* g_w = (const float*)d_in[14];
    const float* g_b = (const float*)d_in[15];
    float* out = (float*)d_out;

    char* ws = (char*)d_ws;
    int*   didx   = (int*)ws;                       // [ 0.0,  2.0 MB)
    float* wq     = (float*)(ws + 2000000);         // [ 2.0,  8.4 MB)
    float* qb     = (float*)(ws + 8400000);         // [ 8.4,  8.6 MB)
    float* ctxw   = (float*)(ws + 8600000);         // [ 8.6, 15.0 MB)  ctxbits -> ctxW2b
    float* comp   = (float*)(ws + 15000000);        // [15.0, 17.0 MB)
    float* segmax = (float*)(ws + 17000000);        // [17.0, 17.2 MB)
    short* Wf     = (short*)(ws + 17200000);        // 32 KB
    short* W1f    = (short*)(ws + 17240000);        // 2 KB
    short* W2af   = (short*)(ws + 17244000);        // 2 KB
    short* W2f    = (short*)(ws + 17248000);        // 32 KB
    float* invsum = (float*)(ws + 17300000);        // 200 KB
    short* hbuf   = (short*)(ws + 17500000);        // 32 MB
    float* pooled = out;

    k0_setup<<<512, 256, 0, stream>>>(csr, W_mod1, W_mod2, W_map1, W_map2,
                                      didx, pooled, ctxw, Wf, W1f, W2af, W2f);
    kHA<<<KH_BLOCKS + KA_BLOCKS, 256, 0, stream>>>(x_map, didx, W1f, (int*)ctxw, hbuf,
                                                   x_main, W_main1, W_main2, WQ, bQ,
                                                   WK, bK, wq, qb);
    kB2b_ctxw<<<(N_PTS + 7) / 8, 256, 0, stream>>>(W_map2, ctxw);
    kB3_comp<<<(V_VIEWS + 63) / 64, 256, 0, stream>>>(hbuf, didx, W2af,
                                                      ctxw, wq, qb, comp);
    kB4_att<<<(N_PTS + 3) / 4, 256, 0, stream>>>(comp, csr, segmax, invsum);
    kC_pool<<<(V_VIEWS + VB - 1) / VB, 256, 0, stream>>>(x_mod, Wf, didx, csr,
                                                         comp, segmax, invsum, pooled);
    kD_final<<<(N_PTS + 63) / 64, 256, 0, stream>>>(W2f, segmax, csr, g_w, g_b, out);
}